// Round 2
// baseline (323.561 us; speedup 1.0000x reference)
//
#include <hip/hip_runtime.h>

// Problem constants (from reference):
//   B=32, L=2048, KD=512, QD=512, H=4, D=128, H*D=512
// Key insight: softmax over the SINGLETON query axis -> aw == 1.0 everywhere.
//   cv[b]  = (sum_l value[b,l,:]) @ Wv @ Wo + bo      [32 x 512]
//   aw_out = ones(H*B, 1, L)                          [128 x 2048]
// key, query, key_lens, Wk, Wq are dead inputs.

#define BB 32
#define LL 2048
#define HD 512          // H*D == KD
#define NCH 32          // L-chunks per batch
#define ROWS_PER_CH (LL / NCH)   // 64

// ---------------------------------------------------------------------------
// Kernel 1: partial[b*NCH+ch][c] = sum over 64 rows of value[b][l][c]
// 1024 blocks x 256 threads; float4 coalesced; deterministic (no atomics).
// ---------------------------------------------------------------------------
__global__ __launch_bounds__(256) void reduce_v(const float* __restrict__ value,
                                                float* __restrict__ partial) {
    const int blk = blockIdx.x;            // b*NCH + ch
    const int b   = blk >> 5;              // /32
    const int ch  = blk & 31;
    const int tid = threadIdx.x;
    const int c4  = tid & 127;             // float4 column (512 floats = 128 float4)
    const int rh  = tid >> 7;              // 0..1 row phase

    const float4* src = (const float4*)(value + (size_t)b * LL * HD)
                        + (size_t)(ch * ROWS_PER_CH) * 128 + c4;
    float4 acc = make_float4(0.f, 0.f, 0.f, 0.f);
    #pragma unroll 8
    for (int l = rh; l < ROWS_PER_CH; l += 2) {
        float4 v = src[(size_t)l * 128];
        acc.x += v.x; acc.y += v.y; acc.z += v.z; acc.w += v.w;
    }

    __shared__ float4 sh[2][128];
    sh[rh][c4] = acc;
    __syncthreads();
    if (rh == 0) {
        float4 a = sh[0][c4], bsum = sh[1][c4];
        float4 r = make_float4(a.x + bsum.x, a.y + bsum.y, a.z + bsum.z, a.w + bsum.w);
        ((float4*)partial)[(size_t)blk * 128 + c4] = r;
    }
}

// ---------------------------------------------------------------------------
// Kernel 2: per-b chunk-reduce then cv[b] = (sv @ Wv) @ Wo + bo
// 32 blocks x 512 threads; weights are 2 MB total -> L2-resident.
// ---------------------------------------------------------------------------
__global__ __launch_bounds__(512) void matmul2(const float* __restrict__ partial,
                                               const float* __restrict__ Wv,
                                               const float* __restrict__ Wo,
                                               const float* __restrict__ bo,
                                               float* __restrict__ cv) {
    const int b = blockIdx.x;
    const int j = threadIdx.x;   // output column 0..511

    __shared__ float sv[HD];
    __shared__ float tmp[HD];

    // reduce the 32 chunk partials for column j (coalesced across j)
    float s = 0.f;
    const float* p = partial + (size_t)b * NCH * HD + j;
    #pragma unroll
    for (int ch = 0; ch < NCH; ++ch) s += p[(size_t)ch * HD];
    sv[j] = s;
    __syncthreads();

    // tmp[j] = dot(sv, Wv[:, j])
    float t = 0.f;
    #pragma unroll 8
    for (int c = 0; c < HD; ++c) t += sv[c] * Wv[(size_t)c * HD + j];
    tmp[j] = t;
    __syncthreads();

    // out[j] = dot(tmp, Wo[:, j]) + bo[j]
    float o = bo[j];
    #pragma unroll 8
    for (int c = 0; c < HD; ++c) o += tmp[c] * Wo[(size_t)c * HD + j];
    cv[(size_t)b * HD + j] = o;
}

// ---------------------------------------------------------------------------
// Kernel 3: aw_out = 1.0f everywhere (H*B*L = 262144 floats = 65536 float4)
// ---------------------------------------------------------------------------
__global__ __launch_bounds__(256) void fill_ones(float4* __restrict__ out) {
    const int i = blockIdx.x * 256 + threadIdx.x;
    out[i] = make_float4(1.f, 1.f, 1.f, 1.f);
}

extern "C" void kernel_launch(void* const* d_in, const int* in_sizes, int n_in,
                              void* d_out, int out_size, void* d_ws, size_t ws_size,
                              hipStream_t stream) {
    // setup_inputs order: key(0) value(1) query(2) key_lens(3) Wk(4) Wv(5) Wq(6) Wo(7) bo(8)
    const float* value = (const float*)d_in[1];
    const float* Wv    = (const float*)d_in[5];
    const float* Wo    = (const float*)d_in[7];
    const float* bo    = (const float*)d_in[8];

    float* out = (float*)d_out;
    float* cv  = out;                 // [B,1,KD] = 16384 floats
    float* aw  = out + BB * HD;       // [H*B,1,L] = 262144 floats

    float* partial = (float*)d_ws;    // BB*NCH*HD floats = 2 MiB

    reduce_v<<<BB * NCH, 256, 0, stream>>>(value, partial);
    matmul2<<<BB, 512, 0, stream>>>(partial, Wv, Wo, bo, cv);
    fill_ones<<<(BB * 4 * LL) / 4 / 256, 256, 0, stream>>>((float4*)aw);
}